// Round 4
// baseline (338.387 us; speedup 1.0000x reference)
//
#include <hip/hip_runtime.h>
#include <hip/hip_bf16.h>
#include <hip/hip_fp16.h>

#define C_DIM 64
#define M_DIM 8
#define O_DIM 64

typedef _Float16 h8 __attribute__((ext_vector_type(8)));
typedef _Float16 h2v __attribute__((ext_vector_type(2)));
typedef float f32x4 __attribute__((ext_vector_type(4)));

union HU { unsigned int u; h2v h; };

__device__ __forceinline__ unsigned int packh2(float a, float b) {
    HU x;
    x.h[0] = (_Float16)a;
    x.h[1] = (_Float16)b;
    return x.u;
}
__device__ __forceinline__ int rfl(int x) { return __builtin_amdgcn_readfirstlane(x); }

// Fused prep: xu = data@var_u (8 thr/vertex), data->f16 convert, edge histogram.
__global__ __launch_bounds__(256) void prep_kernel(
    const float* __restrict__ data, const float* __restrict__ u,
    const int* __restrict__ esrc, float* __restrict__ xu,
    unsigned short* __restrict__ datah, int* __restrict__ counts, int V, int E) {
    int b = blockIdx.x, t = threadIdx.x;
    // xu: 32 vertices per block, 8 threads per vertex
    int v = b * 32 + (t >> 3), m = t & 7;
    if (v < V) {
        const float* dr = data + (size_t)v * C_DIM;
        float s = 0.f;
#pragma unroll
        for (int c = 0; c < C_DIM; ++c) s = fmaf(dr[c], u[c * M_DIM + m], s);
        xu[(size_t)v * 8 + m] = s;
    }
    // data -> f16: 2048 elements per block, 8 per thread
    size_t base = (size_t)b * 2048 + (size_t)t * 8;
    if (base + 7 < (size_t)V * C_DIM) {
        f32x4 x0 = *(const f32x4*)&data[base];
        f32x4 x1 = *(const f32x4*)&data[base + 4];
        uint4 o;
        o.x = packh2(x0[0], x0[1]);
        o.y = packh2(x0[2], x0[3]);
        o.z = packh2(x1[0], x1[1]);
        o.w = packh2(x1[2], x1[3]);
        *(uint4*)&datah[base] = o;
    }
    // histogram over edges (grid-stride)
    int stride = gridDim.x * 256;
    for (int e = b * 256 + t; e < E; e += stride) atomicAdd(&counts[esrc[e]], 1);
}

// Repack var_w [M,C,O] into MFMA B-fragment order (f16):
// bfrag[((kt*4+nt)*64 + lane)*8 + j] = f16( Wflat[kt*32 + (lane>>4)*8 + j][nt*16 + (lane&15)] )
__global__ void wb_kernel(const float* __restrict__ w, _Float16* __restrict__ bfrag) {
    int t = blockIdx.x * blockDim.x + threadIdx.x;
    if (t >= 16 * 4 * 64) return;
    int kt = t >> 8;
    int rem = t & 255;
    int nt = rem >> 6;
    int lane = rem & 63;
    int quad = lane >> 4;
    int n = nt * 16 + (lane & 15);
#pragma unroll
    for (int j = 0; j < 8; ++j) {
        int k = kt * 32 + quad * 8 + j;
        bfrag[(size_t)t * 8 + j] = (_Float16)w[k * 64 + n];
    }
}

// Block-level inclusive scan (Hillis-Steele) + block sums
__global__ void scan_a(const int* __restrict__ counts, int* __restrict__ incl,
                       int* __restrict__ bsums, int V) {
    __shared__ int s[1024];
    int g = blockIdx.x * 1024 + threadIdx.x;
    int x = (g < V) ? counts[g] : 0;
    s[threadIdx.x] = x;
    __syncthreads();
    for (int off = 1; off < 1024; off <<= 1) {
        int add = (threadIdx.x >= off) ? s[threadIdx.x - off] : 0;
        __syncthreads();
        s[threadIdx.x] += add;
        __syncthreads();
    }
    if (g < V) incl[g] = s[threadIdx.x];
    if (threadIdx.x == 1023) bsums[blockIdx.x] = s[1023];
}

// Finalize exclusive offsets; per-block prefix over bsums computed in-kernel
// (kills the serial scan_b kernel). Assumes nb <= 1024.
__global__ void scan_c2(const int* __restrict__ counts, const int* __restrict__ incl,
                        const int* __restrict__ bsums, int* __restrict__ offsets,
                        int V, int nb) {
    __shared__ int sb[1024];
    int tid = threadIdx.x;
    sb[tid] = (tid < nb) ? bsums[tid] : 0;
    __syncthreads();
    int base = 0;
    for (int i = 0; i < blockIdx.x; ++i) base += sb[i];  // LDS broadcast reads
    int g = blockIdx.x * 1024 + tid;
    if (g < V) offsets[g] = base + incl[g] - counts[g];
}

// Scatter only the 4 B edge id into its CSR slot (region L2-resident).
__global__ __launch_bounds__(256) void eid_scatter_kernel(
    const int* __restrict__ src, const int* __restrict__ offsets,
    int* __restrict__ cursor, int* __restrict__ es_eid, int E) {
    int e = blockIdx.x * blockDim.x + threadIdx.x;
    if (e >= E) return;
    int s = src[e];
    int pos = offsets[s] + atomicAdd(&cursor[s], 1);
    es_eid[pos] = e;
}

// Fused: per 16-vertex tile.
// Phase A (per 64-edge chunk): one edge per lane -> softmax gates (f16) to LDS.
// Phase B: per-edge datah gather + 8x fma_mix, gates via LDS broadcast.
// Then 16x16x32 f16 MFMA epilogue.
#define A_STRIDE 520
__global__ __launch_bounds__(256) void fused_kernel(
    const unsigned short* __restrict__ datah, const int* __restrict__ es_eid,
    const int* __restrict__ edst, const float* __restrict__ ew,
    const float* __restrict__ xu, const float* __restrict__ vc,
    const int* __restrict__ counts, const int* __restrict__ offsets,
    const _Float16* __restrict__ bfragG, const float* __restrict__ bias,
    float* __restrict__ out, int V) {
    __shared__ _Float16 At[16 * A_STRIDE];
    __shared__ int ebj[4][64];
    __shared__ uint4 ebq[4][64];
    int wave = rfl(threadIdx.x >> 6);
    int lane = threadIdx.x & 63;
    int v_base = blockIdx.x * 16;

    for (int i = 0; i < 4; ++i) {
        int row = wave * 4 + i;
        int v = v_base + row;
        float acc[8] = {0.f, 0.f, 0.f, 0.f, 0.f, 0.f, 0.f, 0.f};
        if (v < V) {
            int deg = rfl(counts[v]);
            int off = rfl(offsets[v]);
            float xsc[8];
#pragma unroll
            for (int m = 0; m < 8; ++m) xsc[m] = xu[(size_t)v * 8 + m] + vc[m];

            for (int t0 = 0; t0 < deg; t0 += 64) {
                int cnt = min(64, deg - t0);
                // ---- Phase A: one edge per lane ----
                if (lane < cnt) {
                    int eid = es_eid[off + t0 + lane];
                    int j = edst[eid];
                    float w = ew[eid];
                    const float* xjp = xu + (size_t)j * 8;
                    f32x4 xj0 = *(const f32x4*)xjp;
                    f32x4 xj1 = *(const f32x4*)(xjp + 4);
                    float lg[8];
                    float mx = -1e30f;
#pragma unroll
                    for (int m = 0; m < 4; ++m) {
                        lg[m] = xsc[m] - xj0[m];
                        lg[m + 4] = xsc[m + 4] - xj1[m];
                    }
#pragma unroll
                    for (int m = 0; m < 8; ++m) mx = fmaxf(mx, lg[m]);
                    float den = 0.f;
#pragma unroll
                    for (int m = 0; m < 8; ++m) {
                        lg[m] = __expf(lg[m] - mx);
                        den += lg[m];
                    }
                    float inv = w / den;
#pragma unroll
                    for (int m = 0; m < 8; ++m) lg[m] *= inv;
                    uint4 qp;
                    qp.x = packh2(lg[0], lg[1]);
                    qp.y = packh2(lg[2], lg[3]);
                    qp.z = packh2(lg[4], lg[5]);
                    qp.w = packh2(lg[6], lg[7]);
                    ebj[wave][lane] = j;
                    ebq[wave][lane] = qp;
                }
                // ---- Phase B: consume (same wave; no barrier needed) ----
#define CONSUME(uu)                                                            \
    do {                                                                       \
        HU q01, q23, q45, q67;                                                 \
        q01.u = qq[uu].x; q23.u = qq[uu].y;                                    \
        q45.u = qq[uu].z; q67.u = qq[uu].w;                                    \
        float xf = xff[uu];                                                    \
        acc[0] = fmaf((float)q01.h[0], xf, acc[0]);                            \
        acc[1] = fmaf((float)q01.h[1], xf, acc[1]);                            \
        acc[2] = fmaf((float)q23.h[0], xf, acc[2]);                            \
        acc[3] = fmaf((float)q23.h[1], xf, acc[3]);                            \
        acc[4] = fmaf((float)q45.h[0], xf, acc[4]);                            \
        acc[5] = fmaf((float)q45.h[1], xf, acc[5]);                            \
        acc[6] = fmaf((float)q67.h[0], xf, acc[6]);                            \
        acc[7] = fmaf((float)q67.h[1], xf, acc[7]);                            \
    } while (0)
                int t = 0;
                for (; t + 8 <= cnt; t += 8) {
                    int jj[8];
                    uint4 qq[8];
                    float xff[8];
#pragma unroll
                    for (int u = 0; u < 8; ++u) {
                        jj[u] = ebj[wave][t + u];
                        qq[u] = ebq[wave][t + u];
                    }
#pragma unroll
                    for (int u = 0; u < 8; ++u) {
                        HU x;
                        x.u = (unsigned int)datah[(size_t)jj[u] * 64 + lane];
                        xff[u] = (float)x.h[0];
                    }
#pragma unroll
                    for (int u = 0; u < 8; ++u) CONSUME(u);
                }
                for (; t + 4 <= cnt; t += 4) {
                    int jj[4];
                    uint4 qq[4];
                    float xff[4];
#pragma unroll
                    for (int u = 0; u < 4; ++u) {
                        jj[u] = ebj[wave][t + u];
                        qq[u] = ebq[wave][t + u];
                    }
#pragma unroll
                    for (int u = 0; u < 4; ++u) {
                        HU x;
                        x.u = (unsigned int)datah[(size_t)jj[u] * 64 + lane];
                        xff[u] = (float)x.h[0];
                    }
#pragma unroll
                    for (int u = 0; u < 4; ++u) CONSUME(u);
                }
                for (; t < cnt; ++t) {
                    uint4 qq[1];
                    float xff[1];
                    int j0 = ebj[wave][t];
                    qq[0] = ebq[wave][t];
                    HU x;
                    x.u = (unsigned int)datah[(size_t)j0 * 64 + lane];
                    xff[0] = (float)x.h[0];
                    CONSUME(0);
                }
            }
        }
#pragma unroll
        for (int m = 0; m < 8; ++m) At[row * A_STRIDE + m * 64 + lane] = (_Float16)acc[m];
    }
    __syncthreads();

    // MFMA epilogue: wave = output column tile
    f32x4 cacc = {0.f, 0.f, 0.f, 0.f};
    int quad = lane >> 4;
    int r16 = lane & 15;
#pragma unroll
    for (int kt = 0; kt < 16; ++kt) {
        h8 a = *(const h8*)&At[r16 * A_STRIDE + kt * 32 + quad * 8];
        h8 b = *(const h8*)&bfragG[((size_t)(kt * 4 + wave) * 64 + lane) * 8];
        cacc = __builtin_amdgcn_mfma_f32_16x16x32_f16(a, b, cacc, 0, 0, 0);
    }
#pragma unroll
    for (int r = 0; r < 4; ++r) {
        int row = quad * 4 + r;
        int v = v_base + row;
        if (v < V) {
            int o = wave * 16 + r16;
            out[(size_t)v * 64 + o] = cacc[r] + bias[o];
        }
    }
}

extern "C" void kernel_launch(void* const* d_in, const int* in_sizes, int n_in,
                              void* d_out, int out_size, void* d_ws, size_t ws_size,
                              hipStream_t stream) {
    const float* data  = (const float*)d_in[0];
    const int*   esrc  = (const int*)d_in[1];
    const int*   edst  = (const int*)d_in[2];
    const float* ew    = (const float*)d_in[3];
    const float* var_u = (const float*)d_in[4];
    const float* var_c = (const float*)d_in[5];
    const float* var_w = (const float*)d_in[6];
    const float* var_b = (const float*)d_in[7];
    float* out = (float*)d_out;

    int V = in_sizes[0] / C_DIM;
    int E = in_sizes[1];

    char* ws = (char*)d_ws;
    size_t off = 0;
    auto alloc = [&](size_t bytes) -> void* {
        void* p = ws + off;
        off = (off + bytes + 255) & ~(size_t)255;
        return p;
    };
    float*     xu      = (float*)alloc((size_t)V * 8 * 4);
    int*       cc      = (int*)alloc((size_t)V * 2 * 4);  // counts | cursor
    int*       counts  = cc;
    int*       cursor  = cc + V;
    int*       offsets = (int*)alloc((size_t)V * 4);
    int*       incl    = (int*)alloc((size_t)V * 4);
    int*       bsums   = (int*)alloc(4096);
    int*       es_eid  = (int*)alloc((size_t)E * 4);
    _Float16*  bfrag   = (_Float16*)alloc((size_t)512 * 64 * 2);
    unsigned short* datah = (unsigned short*)alloc((size_t)V * 64 * 2);

    hipMemsetAsync(cc, 0, (size_t)V * 2 * 4, stream);

    int pb = (V + 31) / 32;
    prep_kernel<<<pb, 256, 0, stream>>>(data, var_u, esrc, xu, datah, counts, V, E);
    wb_kernel<<<16, 256, 0, stream>>>(var_w, bfrag);

    int nb = (V + 1023) / 1024;
    scan_a<<<nb, 1024, 0, stream>>>(counts, incl, bsums, V);
    scan_c2<<<nb, 1024, 0, stream>>>(counts, incl, bsums, offsets, V, nb);

    eid_scatter_kernel<<<(E + 255) / 256, 256, 0, stream>>>(esrc, offsets, cursor,
                                                            es_eid, E);
    fused_kernel<<<(V + 15) / 16, 256, 0, stream>>>(datah, es_eid, edst, ew, xu, var_c,
                                                    counts, offsets, bfrag, var_b, out, V);
}

// Round 5
// 250.491 us; speedup vs baseline: 1.3509x; 1.3509x over previous
//
#include <hip/hip_runtime.h>
#include <hip/hip_bf16.h>
#include <hip/hip_fp16.h>

#define C_DIM 64
#define M_DIM 8
#define O_DIM 64

typedef _Float16 h8 __attribute__((ext_vector_type(8)));
typedef float f32x4 __attribute__((ext_vector_type(4)));

union HH { __half2 h2; unsigned int u; _Float16 f2[2]; };

__device__ __forceinline__ unsigned int packh2(float a, float b) {
    HH x;
    x.f2[0] = (_Float16)a;
    x.f2[1] = (_Float16)b;
    return x.u;
}
__device__ __forceinline__ int rfl(int x) { return __builtin_amdgcn_readfirstlane(x); }

// Fused prep: xu=data@var_u -> f16 rows, data->f16, histogram + per-edge rank.
__global__ __launch_bounds__(256) void prep_kernel(
    const float* __restrict__ data, const float* __restrict__ u,
    const int* __restrict__ esrc, _Float16* __restrict__ xuh,
    unsigned short* __restrict__ datah, int* __restrict__ counts,
    int* __restrict__ rank, int V, int E) {
    int b = blockIdx.x, t = threadIdx.x;
    // xu: 32 vertices per block, 8 threads per vertex
    int v = b * 32 + (t >> 3), m = t & 7;
    if (v < V) {
        const float* dr = data + (size_t)v * C_DIM;
        float s = 0.f;
#pragma unroll
        for (int c = 0; c < C_DIM; ++c) s = fmaf(dr[c], u[c * M_DIM + m], s);
        xuh[(size_t)v * 8 + m] = (_Float16)s;
    }
    // data -> f16: 2048 elements per block, 8 per thread
    size_t base = (size_t)b * 2048 + (size_t)t * 8;
    if (base + 7 < (size_t)V * C_DIM) {
        f32x4 x0 = *(const f32x4*)&data[base];
        f32x4 x1 = *(const f32x4*)&data[base + 4];
        uint4 o;
        o.x = packh2(x0[0], x0[1]);
        o.y = packh2(x0[2], x0[3]);
        o.z = packh2(x1[0], x1[1]);
        o.w = packh2(x1[2], x1[3]);
        *(uint4*)&datah[base] = o;
    }
    // histogram + rank (grid-stride); the atomic's return IS the CSR rank
    int stride = gridDim.x * 256;
    for (int e = b * 256 + t; e < E; e += stride)
        rank[e] = atomicAdd(&counts[esrc[e]], 1);
}

// Repack var_w [M,C,O] into MFMA B-fragment order (f16)
__global__ void wb_kernel(const float* __restrict__ w, _Float16* __restrict__ bfrag) {
    int t = blockIdx.x * blockDim.x + threadIdx.x;
    if (t >= 16 * 4 * 64) return;
    int kt = t >> 8;
    int rem = t & 255;
    int nt = rem >> 6;
    int lane = rem & 63;
    int quad = lane >> 4;
    int n = nt * 16 + (lane & 15);
#pragma unroll
    for (int j = 0; j < 8; ++j) {
        int k = kt * 32 + quad * 8 + j;
        bfrag[(size_t)t * 8 + j] = (_Float16)w[k * 64 + n];
    }
}

// Block-level inclusive scan + block sums
__global__ void scan_a(const int* __restrict__ counts, int* __restrict__ incl,
                       int* __restrict__ bsums, int V) {
    __shared__ int s[1024];
    int g = blockIdx.x * 1024 + threadIdx.x;
    int x = (g < V) ? counts[g] : 0;
    s[threadIdx.x] = x;
    __syncthreads();
    for (int off = 1; off < 1024; off <<= 1) {
        int add = (threadIdx.x >= off) ? s[threadIdx.x - off] : 0;
        __syncthreads();
        s[threadIdx.x] += add;
        __syncthreads();
    }
    if (g < V) incl[g] = s[threadIdx.x];
    if (threadIdx.x == 1023) bsums[blockIdx.x] = s[1023];
}

// Finalize exclusive offsets; block-sum prefix computed in-kernel (nb <= 1024)
__global__ void scan_c2(const int* __restrict__ counts, const int* __restrict__ incl,
                        const int* __restrict__ bsums, int* __restrict__ offsets,
                        int V, int nb) {
    __shared__ int sb[1024];
    int tid = threadIdx.x;
    sb[tid] = (tid < nb) ? bsums[tid] : 0;
    __syncthreads();
    int base = 0;
    for (int i = 0; i < blockIdx.x; ++i) base += sb[i];
    int g = blockIdx.x * 1024 + tid;
    if (g < V) offsets[g] = base + incl[g] - counts[g];
}

// Atomic-free CSR placement: scatter {dst, weight} (8 B) into slot offsets[s]+rank.
__global__ __launch_bounds__(256) void place_kernel(
    const int* __restrict__ esrc, const int* __restrict__ edst,
    const float* __restrict__ ew, const int* __restrict__ offsets,
    const int* __restrict__ rank, uint2* __restrict__ recs, int E) {
    int e = blockIdx.x * blockDim.x + threadIdx.x;
    if (e >= E) return;
    int pos = offsets[esrc[e]] + rank[e];
    uint2 r;
    r.x = (unsigned int)edst[e];
    r.y = __float_as_uint(ew[e]);
    recs[pos] = r;
}

// Fused: per 16-vertex tile.
// Phase A (per 64-edge chunk): one edge/lane; contiguous {j,w} record read,
//   xuh[j] gather (16 B, L2-hot), softmax -> packed f16 gates to LDS.
// Phase B: per-edge datah row gather (1 line) + 4x v_pk_fma_f16 over m-pairs.
// Epilogue: 16x16x32 f16 MFMA.
#define A_STRIDE 520
__global__ __launch_bounds__(256) void fused_kernel(
    const unsigned short* __restrict__ datah, const uint2* __restrict__ recs,
    const _Float16* __restrict__ xuh, const float* __restrict__ vc,
    const int* __restrict__ counts, const int* __restrict__ offsets,
    const _Float16* __restrict__ bfragG, const float* __restrict__ bias,
    float* __restrict__ out, int V) {
    __shared__ _Float16 At[16 * A_STRIDE];
    __shared__ int ebj[4][64];
    __shared__ uint4 ebq[4][64];
    int wave = rfl(threadIdx.x >> 6);
    int lane = threadIdx.x & 63;
    int v_base = blockIdx.x * 16;

    for (int i = 0; i < 4; ++i) {
        int row = wave * 4 + i;
        int v = v_base + row;
        __half2 acc01 = __floats2half2_rn(0.f, 0.f);
        __half2 acc23 = acc01, acc45 = acc01, acc67 = acc01;
        if (v < V) {
            int deg = rfl(counts[v]);
            int off = rfl(offsets[v]);
            float xsc[8];
            {
                uint4 xv = *(const uint4*)&xuh[(size_t)v * 8];
                HH a, b, c, d;
                a.u = xv.x; b.u = xv.y; c.u = xv.z; d.u = xv.w;
                xsc[0] = (float)a.f2[0] + vc[0];
                xsc[1] = (float)a.f2[1] + vc[1];
                xsc[2] = (float)b.f2[0] + vc[2];
                xsc[3] = (float)b.f2[1] + vc[3];
                xsc[4] = (float)c.f2[0] + vc[4];
                xsc[5] = (float)c.f2[1] + vc[5];
                xsc[6] = (float)d.f2[0] + vc[6];
                xsc[7] = (float)d.f2[1] + vc[7];
            }

            for (int t0 = 0; t0 < deg; t0 += 64) {
                int cnt = min(64, deg - t0);
                // ---- Phase A: one edge per lane ----
                if (lane < cnt) {
                    uint2 rec = recs[off + t0 + lane];
                    int j = (int)rec.x;
                    float w = __uint_as_float(rec.y);
                    uint4 xr = *(const uint4*)&xuh[(size_t)j * 8];
                    HH a, b, c, d;
                    a.u = xr.x; b.u = xr.y; c.u = xr.z; d.u = xr.w;
                    float lg[8];
                    lg[0] = xsc[0] - (float)a.f2[0];
                    lg[1] = xsc[1] - (float)a.f2[1];
                    lg[2] = xsc[2] - (float)b.f2[0];
                    lg[3] = xsc[3] - (float)b.f2[1];
                    lg[4] = xsc[4] - (float)c.f2[0];
                    lg[5] = xsc[5] - (float)c.f2[1];
                    lg[6] = xsc[6] - (float)d.f2[0];
                    lg[7] = xsc[7] - (float)d.f2[1];
                    float mx = -1e30f;
#pragma unroll
                    for (int m = 0; m < 8; ++m) mx = fmaxf(mx, lg[m]);
                    float den = 0.f;
#pragma unroll
                    for (int m = 0; m < 8; ++m) {
                        lg[m] = __expf(lg[m] - mx);
                        den += lg[m];
                    }
                    float inv = w / den;
#pragma unroll
                    for (int m = 0; m < 8; ++m) lg[m] *= inv;
                    uint4 qp;
                    qp.x = packh2(lg[0], lg[1]);
                    qp.y = packh2(lg[2], lg[3]);
                    qp.z = packh2(lg[4], lg[5]);
                    qp.w = packh2(lg[6], lg[7]);
                    ebj[wave][lane] = (int)rec.x;
                    ebq[wave][lane] = qp;
                }
                // ---- Phase B: consume (same wave, in-order LDS) ----
#define CONSUME(uu)                                                            \
    do {                                                                       \
        HH q01, q23, q45, q67, xx;                                             \
        q01.u = qq[uu].x; q23.u = qq[uu].y;                                    \
        q45.u = qq[uu].z; q67.u = qq[uu].w;                                    \
        unsigned int xv = (unsigned int)xs[uu];                                \
        xx.u = xv | (xv << 16);                                                \
        acc01 = __hfma2(xx.h2, q01.h2, acc01);                                 \
        acc23 = __hfma2(xx.h2, q23.h2, acc23);                                 \
        acc45 = __hfma2(xx.h2, q45.h2, acc45);                                 \
        acc67 = __hfma2(xx.h2, q67.h2, acc67);                                 \
    } while (0)
                int t = 0;
                for (; t + 8 <= cnt; t += 8) {
                    int jj[8];
                    uint4 qq[8];
                    unsigned short xs[8];
#pragma unroll
                    for (int u = 0; u < 8; ++u) {
                        jj[u] = ebj[wave][t + u];
                        qq[u] = ebq[wave][t + u];
                    }
#pragma unroll
                    for (int u = 0; u < 8; ++u)
                        xs[u] = datah[(size_t)jj[u] * 64 + lane];
#pragma unroll
                    for (int u = 0; u < 8; ++u) CONSUME(u);
                }
                for (; t + 4 <= cnt; t += 4) {
                    int jj[4];
                    uint4 qq[4];
                    unsigned short xs[4];
#pragma unroll
                    for (int u = 0; u < 4; ++u) {
                        jj[u] = ebj[wave][t + u];
                        qq[u] = ebq[wave][t + u];
                    }
#pragma unroll
                    for (int u = 0; u < 4; ++u)
                        xs[u] = datah[(size_t)jj[u] * 64 + lane];
#pragma unroll
                    for (int u = 0; u < 4; ++u) CONSUME(u);
                }
                for (; t < cnt; ++t) {
                    uint4 qq[1];
                    unsigned short xs[1];
                    int j0 = ebj[wave][t];
                    qq[0] = ebq[wave][t];
                    xs[0] = datah[(size_t)j0 * 64 + lane];
                    CONSUME(0);
                }
            }
        }
        {
            HH a01, a23, a45, a67;
            a01.h2 = acc01; a23.h2 = acc23; a45.h2 = acc45; a67.h2 = acc67;
            _Float16* Ar = &At[row * A_STRIDE + lane];
            Ar[0 * 64] = a01.f2[0];
            Ar[1 * 64] = a01.f2[1];
            Ar[2 * 64] = a23.f2[0];
            Ar[3 * 64] = a23.f2[1];
            Ar[4 * 64] = a45.f2[0];
            Ar[5 * 64] = a45.f2[1];
            Ar[6 * 64] = a67.f2[0];
            Ar[7 * 64] = a67.f2[1];
        }
    }
    __syncthreads();

    // MFMA epilogue: wave = output column tile
    f32x4 cacc = {0.f, 0.f, 0.f, 0.f};
    int quad = lane >> 4;
    int r16 = lane & 15;
#pragma unroll
    for (int kt = 0; kt < 16; ++kt) {
        h8 a = *(const h8*)&At[r16 * A_STRIDE + kt * 32 + quad * 8];
        h8 b = *(const h8*)&bfragG[((size_t)(kt * 4 + wave) * 64 + lane) * 8];
        cacc = __builtin_amdgcn_mfma_f32_16x16x32_f16(a, b, cacc, 0, 0, 0);
    }
#pragma unroll
    for (int r = 0; r < 4; ++r) {
        int row = quad * 4 + r;
        int v = v_base + row;
        if (v < V) {
            int o = wave * 16 + r16;
            out[(size_t)v * 64 + o] = cacc[r] + bias[o];
        }
    }
}

extern "C" void kernel_launch(void* const* d_in, const int* in_sizes, int n_in,
                              void* d_out, int out_size, void* d_ws, size_t ws_size,
                              hipStream_t stream) {
    const float* data  = (const float*)d_in[0];
    const int*   esrc  = (const int*)d_in[1];
    const int*   edst  = (const int*)d_in[2];
    const float* ew    = (const float*)d_in[3];
    const float* var_u = (const float*)d_in[4];
    const float* var_c = (const float*)d_in[5];
    const float* var_w = (const float*)d_in[6];
    const float* var_b = (const float*)d_in[7];
    float* out = (float*)d_out;

    int V = in_sizes[0] / C_DIM;
    int E = in_sizes[1];

    char* ws = (char*)d_ws;
    size_t off = 0;
    auto alloc = [&](size_t bytes) -> void* {
        void* p = ws + off;
        off = (off + bytes + 255) & ~(size_t)255;
        return p;
    };
    _Float16*  xuh     = (_Float16*)alloc((size_t)V * 8 * 2);
    int*       counts  = (int*)alloc((size_t)V * 4);
    int*       offsets = (int*)alloc((size_t)V * 4);
    int*       incl    = (int*)alloc((size_t)V * 4);
    int*       bsums   = (int*)alloc(4096);
    int*       rank    = (int*)alloc((size_t)E * 4);
    uint2*     recs    = (uint2*)alloc((size_t)E * 8);
    _Float16*  bfrag   = (_Float16*)alloc((size_t)512 * 64 * 2);
    unsigned short* datah = (unsigned short*)alloc((size_t)V * 64 * 2);

    hipMemsetAsync(counts, 0, (size_t)V * 4, stream);

    int pb = (V + 31) / 32;
    prep_kernel<<<pb, 256, 0, stream>>>(data, var_u, esrc, xuh, datah, counts, rank, V, E);
    wb_kernel<<<16, 256, 0, stream>>>(var_w, bfrag);

    int nb = (V + 1023) / 1024;
    scan_a<<<nb, 1024, 0, stream>>>(counts, incl, bsums, V);
    scan_c2<<<nb, 1024, 0, stream>>>(counts, incl, bsums, offsets, V, nb);

    place_kernel<<<(E + 255) / 256, 256, 0, stream>>>(esrc, edst, ew, offsets, rank,
                                                      recs, E);
    fused_kernel<<<(V + 15) / 16, 256, 0, stream>>>(datah, recs, xuh, var_c,
                                                    counts, offsets, bfrag, var_b, out, V);
}

// Round 6
// 240.205 us; speedup vs baseline: 1.4087x; 1.0428x over previous
//
#include <hip/hip_runtime.h>
#include <hip/hip_bf16.h>
#include <hip/hip_fp16.h>

#define C_DIM 64
#define M_DIM 8
#define O_DIM 64

typedef _Float16 h8 __attribute__((ext_vector_type(8)));
typedef float f32x4 __attribute__((ext_vector_type(4)));

union HH { __half2 h2; unsigned int u; _Float16 f2[2]; };

__device__ __forceinline__ unsigned int packh2(float a, float b) {
    HH x;
    x.f2[0] = (_Float16)a;
    x.f2[1] = (_Float16)b;
    return x.u;
}
__device__ __forceinline__ int rfl(int x) { return __builtin_amdgcn_readfirstlane(x); }

// Fused prep: xu=data@var_u -> f16 rows, data->f16, histogram + per-edge rank.
__global__ __launch_bounds__(256) void prep_kernel(
    const float* __restrict__ data, const float* __restrict__ u,
    const int* __restrict__ esrc, _Float16* __restrict__ xuh,
    unsigned short* __restrict__ datah, int* __restrict__ counts,
    int* __restrict__ rank, int V, int E) {
    int b = blockIdx.x, t = threadIdx.x;
    int v = b * 32 + (t >> 3), m = t & 7;
    if (v < V) {
        const float* dr = data + (size_t)v * C_DIM;
        float s = 0.f;
#pragma unroll
        for (int c = 0; c < C_DIM; ++c) s = fmaf(dr[c], u[c * M_DIM + m], s);
        xuh[(size_t)v * 8 + m] = (_Float16)s;
    }
    size_t base = (size_t)b * 2048 + (size_t)t * 8;
    if (base + 7 < (size_t)V * C_DIM) {
        f32x4 x0 = *(const f32x4*)&data[base];
        f32x4 x1 = *(const f32x4*)&data[base + 4];
        uint4 o;
        o.x = packh2(x0[0], x0[1]);
        o.y = packh2(x0[2], x0[3]);
        o.z = packh2(x1[0], x1[1]);
        o.w = packh2(x1[2], x1[3]);
        *(uint4*)&datah[base] = o;
    }
    int stride = gridDim.x * 256;
    for (int e = b * 256 + t; e < E; e += stride)
        rank[e] = atomicAdd(&counts[esrc[e]], 1);
}

// Repack var_w [M,C,O] into MFMA B-fragment order (f16)
__global__ void wb_kernel(const float* __restrict__ w, _Float16* __restrict__ bfrag) {
    int t = blockIdx.x * blockDim.x + threadIdx.x;
    if (t >= 16 * 4 * 64) return;
    int kt = t >> 8;
    int rem = t & 255;
    int nt = rem >> 6;
    int lane = rem & 63;
    int quad = lane >> 4;
    int n = nt * 16 + (lane & 15);
#pragma unroll
    for (int j = 0; j < 8; ++j) {
        int k = kt * 32 + quad * 8 + j;
        bfrag[(size_t)t * 8 + j] = (_Float16)w[k * 64 + n];
    }
}

// Block-level inclusive scan + block sums
__global__ void scan_a(const int* __restrict__ counts, int* __restrict__ incl,
                       int* __restrict__ bsums, int V) {
    __shared__ int s[1024];
    int g = blockIdx.x * 1024 + threadIdx.x;
    int x = (g < V) ? counts[g] : 0;
    s[threadIdx.x] = x;
    __syncthreads();
    for (int off = 1; off < 1024; off <<= 1) {
        int add = (threadIdx.x >= off) ? s[threadIdx.x - off] : 0;
        __syncthreads();
        s[threadIdx.x] += add;
        __syncthreads();
    }
    if (g < V) incl[g] = s[threadIdx.x];
    if (threadIdx.x == 1023) bsums[blockIdx.x] = s[1023];
}

// Finalize exclusive offsets; block-sum prefix computed in-kernel (nb <= 1024)
__global__ void scan_c2(const int* __restrict__ counts, const int* __restrict__ incl,
                        const int* __restrict__ bsums, int* __restrict__ offsets,
                        int V, int nb) {
    __shared__ int sb[1024];
    int tid = threadIdx.x;
    sb[tid] = (tid < nb) ? bsums[tid] : 0;
    __syncthreads();
    int base = 0;
    for (int i = 0; i < blockIdx.x; ++i) base += sb[i];
    int g = blockIdx.x * 1024 + tid;
    if (g < V) offsets[g] = base + incl[g] - counts[g];
}

// Atomic-free CSR placement: scatter {dst, weight} (8 B) into slot offsets[s]+rank.
__global__ __launch_bounds__(256) void place_kernel(
    const int* __restrict__ esrc, const int* __restrict__ edst,
    const float* __restrict__ ew, const int* __restrict__ offsets,
    const int* __restrict__ rank, uint2* __restrict__ recs, int E) {
    int e = blockIdx.x * blockDim.x + threadIdx.x;
    if (e >= E) return;
    int pos = offsets[esrc[e]] + rank[e];
    uint2 r;
    r.x = (unsigned int)edst[e];
    r.y = __float_as_uint(ew[e]);
    recs[pos] = r;
}

// Fused: per 16-vertex tile, 4 waves x 4 rows.
// Phase A: one edge/lane over the wave's concatenated 4-row CSR range
//   (owner row via prefix compare; owner xsc staged in LDS) -> gates to LDS.
// Phase B: per-row consume; j scalarized (readfirstlane) -> saddr gather;
//   4x v_pk_fma_f16. Same-wave produce/consume: no barriers.
// Epilogue: 16x16x32 f16 MFMA.
#define A_STRIDE 520
__global__ __launch_bounds__(256) void fused_kernel(
    const unsigned short* __restrict__ datah, const uint2* __restrict__ recs,
    const _Float16* __restrict__ xuh, const float* __restrict__ vc,
    const int* __restrict__ counts, const int* __restrict__ offsets,
    const _Float16* __restrict__ bfragG, const float* __restrict__ bias,
    float* __restrict__ out, int V) {
    __shared__ _Float16 At[16 * A_STRIDE];
    __shared__ int ebj[4][64];
    __shared__ uint4 ebq[4][64];
    __shared__ float xscS[4][4][8];
    __shared__ int pS[4][5];
    __shared__ int oS[4][4];
    int wave = rfl(threadIdx.x >> 6);
    int lane = threadIdx.x & 63;
    int v_base = blockIdx.x * 16;
    int v0 = v_base + wave * 4;

    // Per-wave setup: degrees, offsets, prefix, xsc staging (all same-wave LDS)
    if (lane < 4) {
        int v = v0 + lane;
        int dd = (v < V) ? counts[v] : 0;
        int oo = (v < V) ? offsets[v] : 0;
        oS[wave][lane] = oo;
        pS[wave][lane + 1] = dd;
    }
    if (lane == 0) {
        pS[wave][0] = 0;
        int s = 0;
#pragma unroll
        for (int i = 1; i <= 4; ++i) {
            s += pS[wave][i];
            pS[wave][i] = s;
        }
    }
    if (lane < 32) {
        int i = lane >> 3, m = lane & 7;
        int v = v0 + i;
        float s = 0.f;
        if (v < V) s = (float)xuh[(size_t)v0 * 8 + lane] + vc[m];
        xscS[wave][i][m] = s;
    }

    HH z; z.u = 0;
    __half2 acc[4][4];
#pragma unroll
    for (int i = 0; i < 4; ++i)
#pragma unroll
        for (int k = 0; k < 4; ++k) acc[i][k] = z.h2;

    int total = rfl(pS[wave][4]);

    for (int c0 = 0; c0 < total; c0 += 64) {
        // ---- Phase A: one edge per lane across the wave's 4 rows ----
        int g = c0 + lane;
        if (g < total) {
            int p1 = pS[wave][1], p2 = pS[wave][2], p3 = pS[wave][3];
            int r = (g >= p1) + (g >= p2) + (g >= p3);
            int pr = (r > 0) ? ((r > 1) ? ((r > 2) ? p3 : p2) : p1) : 0;
            int ob = oS[wave][r];
            int pos = ob + (g - pr);
            uint2 rec = recs[pos];
            int j = (int)rec.x;
            float w = __uint_as_float(rec.y);
            f32x4 xa = *(const f32x4*)&xscS[wave][r][0];
            f32x4 xb = *(const f32x4*)&xscS[wave][r][4];
            uint4 xr = *(const uint4*)&xuh[(size_t)j * 8];
            HH a, b, c, d;
            a.u = xr.x; b.u = xr.y; c.u = xr.z; d.u = xr.w;
            float lg[8];
            lg[0] = xa[0] - (float)a.f2[0];
            lg[1] = xa[1] - (float)a.f2[1];
            lg[2] = xa[2] - (float)b.f2[0];
            lg[3] = xa[3] - (float)b.f2[1];
            lg[4] = xb[0] - (float)c.f2[0];
            lg[5] = xb[1] - (float)c.f2[1];
            lg[6] = xb[2] - (float)d.f2[0];
            lg[7] = xb[3] - (float)d.f2[1];
            float mx = -1e30f;
#pragma unroll
            for (int m = 0; m < 8; ++m) mx = fmaxf(mx, lg[m]);
            float den = 0.f;
#pragma unroll
            for (int m = 0; m < 8; ++m) {
                lg[m] = __expf(lg[m] - mx);
                den += lg[m];
            }
            float inv = w / den;
#pragma unroll
            for (int m = 0; m < 8; ++m) lg[m] *= inv;
            uint4 qp;
            qp.x = packh2(lg[0], lg[1]);
            qp.y = packh2(lg[2], lg[3]);
            qp.z = packh2(lg[4], lg[5]);
            qp.w = packh2(lg[6], lg[7]);
            ebj[wave][lane] = j;
            ebq[wave][lane] = qp;
        }
        // ---- Phase B: consume this chunk, row by row (same wave) ----
#define CONSUME(rr, uu)                                                        \
    do {                                                                       \
        HH q01, q23, q45, q67, xx;                                             \
        q01.u = qq[uu].x; q23.u = qq[uu].y;                                    \
        q45.u = qq[uu].z; q67.u = qq[uu].w;                                    \
        unsigned int xv = (unsigned int)xs[uu];                                \
        xx.u = xv | (xv << 16);                                                \
        acc[rr][0] = __hfma2(xx.h2, q01.h2, acc[rr][0]);                       \
        acc[rr][1] = __hfma2(xx.h2, q23.h2, acc[rr][1]);                       \
        acc[rr][2] = __hfma2(xx.h2, q45.h2, acc[rr][2]);                       \
        acc[rr][3] = __hfma2(xx.h2, q67.h2, acc[rr][3]);                       \
    } while (0)
#pragma unroll
        for (int r2 = 0; r2 < 4; ++r2) {
            int pr0 = rfl(pS[wave][r2]);
            int pr1 = rfl(pS[wave][r2 + 1]);
            int lo = max(pr0, c0);
            int hi = min(pr1, c0 + 64);
            int n = hi - lo;
            if (n <= 0) continue;
            int tb = lo - c0;
            int t = 0;
            for (; t + 8 <= n; t += 8) {
                uint4 qq[8];
                unsigned short xs[8];
                int jj[8];
#pragma unroll
                for (int u = 0; u < 8; ++u) {
                    jj[u] = rfl(ebj[wave][tb + t + u]);
                    qq[u] = ebq[wave][tb + t + u];
                }
#pragma unroll
                for (int u = 0; u < 8; ++u) {
                    const unsigned short* xp = datah + ((size_t)jj[u] << 6);
                    xs[u] = xp[lane];
                }
#pragma unroll
                for (int u = 0; u < 8; ++u) CONSUME(r2, u);
            }
            for (; t + 4 <= n; t += 4) {
                uint4 qq[4];
                unsigned short xs[4];
                int jj[4];
#pragma unroll
                for (int u = 0; u < 4; ++u) {
                    jj[u] = rfl(ebj[wave][tb + t + u]);
                    qq[u] = ebq[wave][tb + t + u];
                }
#pragma unroll
                for (int u = 0; u < 4; ++u) {
                    const unsigned short* xp = datah + ((size_t)jj[u] << 6);
                    xs[u] = xp[lane];
                }
#pragma unroll
                for (int u = 0; u < 4; ++u) CONSUME(r2, u);
            }
            for (; t < n; ++t) {
                uint4 qq[1];
                unsigned short xs[1];
                int j0 = rfl(ebj[wave][tb + t]);
                qq[0] = ebq[wave][tb + t];
                const unsigned short* xp = datah + ((size_t)j0 << 6);
                xs[0] = xp[lane];
                CONSUME(r2, 0);
            }
        }
    }

    // Deposit A-tile rows
#pragma unroll
    for (int i = 0; i < 4; ++i) {
        int row = wave * 4 + i;
        HH a01, a23, a45, a67;
        a01.h2 = acc[i][0]; a23.h2 = acc[i][1];
        a45.h2 = acc[i][2]; a67.h2 = acc[i][3];
        _Float16* Ar = &At[row * A_STRIDE + lane];
        Ar[0 * 64] = a01.f2[0];
        Ar[1 * 64] = a01.f2[1];
        Ar[2 * 64] = a23.f2[0];
        Ar[3 * 64] = a23.f2[1];
        Ar[4 * 64] = a45.f2[0];
        Ar[5 * 64] = a45.f2[1];
        Ar[6 * 64] = a67.f2[0];
        Ar[7 * 64] = a67.f2[1];
    }
    __syncthreads();

    // MFMA epilogue: wave = output column tile
    f32x4 cacc = {0.f, 0.f, 0.f, 0.f};
    int quad = lane >> 4;
    int r16 = lane & 15;
#pragma unroll
    for (int kt = 0; kt < 16; ++kt) {
        h8 a = *(const h8*)&At[r16 * A_STRIDE + kt * 32 + quad * 8];
        h8 b = *(const h8*)&bfragG[((size_t)(kt * 4 + wave) * 64 + lane) * 8];
        cacc = __builtin_amdgcn_mfma_f32_16x16x32_f16(a, b, cacc, 0, 0, 0);
    }
#pragma unroll
    for (int r = 0; r < 4; ++r) {
        int row = quad * 4 + r;
        int v = v_base + row;
        if (v < V) {
            int o = wave * 16 + r16;
            out[(size_t)v * 64 + o] = cacc[r] + bias[o];
        }
    }
}

extern "C" void kernel_launch(void* const* d_in, const int* in_sizes, int n_in,
                              void* d_out, int out_size, void* d_ws, size_t ws_size,
                              hipStream_t stream) {
    const float* data  = (const float*)d_in[0];
    const int*   esrc  = (const int*)d_in[1];
    const int*   edst  = (const int*)d_in[2];
    const float* ew    = (const float*)d_in[3];
    const float* var_u = (const float*)d_in[4];
    const float* var_c = (const float*)d_in[5];
    const float* var_w = (const float*)d_in[6];
    const float* var_b = (const float*)d_in[7];
    float* out = (float*)d_out;

    int V = in_sizes[0] / C_DIM;
    int E = in_sizes[1];

    char* ws = (char*)d_ws;
    size_t off = 0;
    auto alloc = [&](size_t bytes) -> void* {
        void* p = ws + off;
        off = (off + bytes + 255) & ~(size_t)255;
        return p;
    };
    _Float16*  xuh     = (_Float16*)alloc((size_t)V * 8 * 2);
    int*       counts  = (int*)alloc((size_t)V * 4);
    int*       offsets = (int*)alloc((size_t)V * 4);
    int*       incl    = (int*)alloc((size_t)V * 4);
    int*       bsums   = (int*)alloc(4096);
    int*       rank    = (int*)alloc((size_t)E * 4);
    uint2*     recs    = (uint2*)alloc((size_t)E * 8);
    _Float16*  bfrag   = (_Float16*)alloc((size_t)512 * 64 * 2);
    unsigned short* datah = (unsigned short*)alloc((size_t)V * 64 * 2);

    hipMemsetAsync(counts, 0, (size_t)V * 4, stream);

    int pb = (V + 31) / 32;
    prep_kernel<<<pb, 256, 0, stream>>>(data, var_u, esrc, xuh, datah, counts, rank, V, E);
    wb_kernel<<<16, 256, 0, stream>>>(var_w, bfrag);

    int nb = (V + 1023) / 1024;
    scan_a<<<nb, 1024, 0, stream>>>(counts, incl, bsums, V);
    scan_c2<<<nb, 1024, 0, stream>>>(counts, incl, bsums, offsets, V, nb);

    place_kernel<<<(E + 255) / 256, 256, 0, stream>>>(esrc, edst, ew, offsets, rank,
                                                      recs, E);
    fused_kernel<<<(V + 15) / 16, 256, 0, stream>>>(datah, recs, xuh, var_c,
                                                    counts, offsets, bfrag, var_b, out, V);
}